// Round 6
// baseline (263.201 us; speedup 1.0000x reference)
//
#include <hip/hip_runtime.h>
#include <hip/hip_bf16.h>
#include <math.h>

// ---------------------------------------------------------------------------
// B=1024, D_DATA=16384, D_LAT=256, N_GRID=256. Inputs f32.
// d_out = f32 slots; harness reads high u16 of each slot as bf16 -> store
// (float)__float2bfloat16(v) (proven R6).
//
// Structure (3 launches):
//   init_kernel  : 1x256, cmin buf0/buf1 = ~0 (dist's fused r0 needs it).
//   dist_kernel  : 256x256, dist tiles; row norms sqA/sqB SELF-COMPUTED from
//                  the LDS tiles (no dependency on losses -> dist runs first);
//                  diag = 0 (barrier slots + done counter); fused Boruvka
//                  round-0 phase A into cmin buf0.
//   fused_kernel : 1088x256. Blocks 0..63 = R5 mst VERBATIM (persistent
//                  Boruvka, comp in LDS, redundant phase B, slot barrier).
//                  Blocks 64..1087 = losses (recon/kl), publishing partials
//                  via agent-scope atomic stores + RELEASE done-counter
//                  (dist diag (2,2)). Block 0 tail acquire-polls done==1024,
//                  then silhouette + final. MST (54us latency-bound, 64 CUs)
//                  and losses (~45us HBM-bound) now OVERLAP instead of
//                  serializing (R5 ledger: no data dep until the tail).
//                  No deadlock: mst blocks have lowest IDs (dispatched first,
//                  all resident); losses blocks wait on nothing; blocks 1..63
//                  exit before the tail poll.
//
// ws layout (floats):
//   [0..2047]    cmin buf0 (u64[1024])  init by init_kernel
//   [2048..4095] cmin buf1 (u64[1024])  init by init_kernel
//   [4096..6143] cmin buf2 (u64[1024])  init by mst blocks at start
//   [6144..8191] partials (recon 1024 | kl 1024), agent-atomic u32 stores
//   [8192..]     dist 1024x1024 (4 MB); diag (16b+1,16b+1) barrier slots,
//                diag (2,2) done counter (zeroed by dist_kernel; diag cells
//                never read as distances: phase A skips comp[j]==comp[i])
// ---------------------------------------------------------------------------

#define NBLK 1024
#define PBLK 64

__device__ __forceinline__ float sub2(const float4 a, const float4 b) {
  const float dx = a.x - b.x, dy = a.y - b.y, dz = a.z - b.z, dw = a.w - b.w;
  return dx * dx + dy * dy + dz * dz + dw * dw;
}

__global__ __launch_bounds__(256) void init_kernel(unsigned long long* __restrict__ cminb) {
  const int t = threadIdx.x;
  for (int v = t; v < 2048; v += 256) cminb[v] = ~0ull;
}

__global__ __launch_bounds__(256) void dist_kernel(const float* __restrict__ z,
                                                   float* __restrict__ dist,
                                                   unsigned long long* __restrict__ cmin0) {
  __shared__ float A[64][68];
  __shared__ float Bs[64][68];
  __shared__ float sqA[64];
  __shared__ float sqB[64];
  const int i0 = (blockIdx.x >> 4) * 64, j0 = (blockIdx.x & 15) * 64;
  const int t = threadIdx.x;
  const int tx = t & 15;
  const int ty = t >> 4;
  float acc[4][4] = {};
  float psA = 0.f, psB = 0.f;          // per-thread row-norm partials
  const int sr = t >> 2, sc = (t & 3) * 16;
  for (int k0 = 0; k0 < 256; k0 += 64) {
    __syncthreads();
#pragma unroll
    for (int it = 0; it < 4; ++it) {
      int lin = it * 256 + t;
      int row = lin >> 4, q = lin & 15;
      *(float4*)&A[row][q * 4]  = *(const float4*)(z + (i0 + row) * 256 + k0 + q * 4);
      *(float4*)&Bs[row][q * 4] = *(const float4*)(z + (j0 + row) * 256 + k0 + q * 4);
    }
    __syncthreads();
    // row-norm partials from staged tiles (thread t: row t>>2, 16-col segment)
#pragma unroll
    for (int e = 0; e < 16; ++e) {
      const float va = A[sr][sc + e];  psA += va * va;
      const float vb = Bs[sr][sc + e]; psB += vb * vb;
    }
#pragma unroll 4
    for (int k = 0; k < 64; k += 4) {
      float4 av[4], bv[4];
#pragma unroll
      for (int rr = 0; rr < 4; ++rr) av[rr] = *(const float4*)&A[ty + 16 * rr][k];
#pragma unroll
      for (int cc = 0; cc < 4; ++cc) bv[cc] = *(const float4*)&Bs[tx + 16 * cc][k];
#pragma unroll
      for (int rr = 0; rr < 4; ++rr)
#pragma unroll
        for (int cc = 0; cc < 4; ++cc) {
          acc[rr][cc] += av[rr].x * bv[cc].x;
          acc[rr][cc] += av[rr].y * bv[cc].y;
          acc[rr][cc] += av[rr].z * bv[cc].z;
          acc[rr][cc] += av[rr].w * bv[cc].w;
        }
    }
  }
  // reduce 4 adjacent-lane partials -> sqA/sqB
  {
    float s = psA + __shfl_xor(psA, 1); s += __shfl_xor(s, 2);
    if ((t & 3) == 0) sqA[t >> 2] = s;
    float u = psB + __shfl_xor(psB, 1); u += __shfl_xor(u, 2);
    if ((t & 3) == 0) sqB[t >> 2] = u;
  }
  __syncthreads();
  unsigned long long rowbest[4] = {~0ull, ~0ull, ~0ull, ~0ull};
#pragma unroll
  for (int rr = 0; rr < 4; ++rr) {
    const int i = i0 + ty + 16 * rr;
    const float sqi = sqA[ty + 16 * rr];
#pragma unroll
    for (int cc = 0; cc < 4; ++cc) {
      const int j = j0 + tx + 16 * cc;
      const float d2 = sqi + sqB[tx + 16 * cc] - 2.f * acc[rr][cc];
      const float d = sqrtf(fmaxf(d2, 0.f) + 1e-12f);
      dist[i * 1024 + j] = (j == i) ? 0.f : d;
      if (j != i) {
        const int lo = i < j ? i : j;
        const int hi = i + j - lo;
        const unsigned long long key =
            ((unsigned long long)__float_as_uint(d) << 32)
          | (unsigned long long)((lo << 10) | hi);
        if (key < rowbest[rr]) rowbest[rr] = key;
      }
    }
  }
#pragma unroll
  for (int rr = 0; rr < 4; ++rr) {
    unsigned long long best = rowbest[rr];
#pragma unroll
    for (int off = 8; off; off >>= 1) {
      const unsigned int blo = __shfl_xor((unsigned int)best, off);
      const unsigned int bhi = __shfl_xor((unsigned int)(best >> 32), off);
      const unsigned long long o = ((unsigned long long)bhi << 32) | blo;
      if (o < best) best = o;
    }
    if (tx == 0) {
      unsigned long long* p = &cmin0[i0 + ty + 16 * rr];
      const unsigned long long cur =
          __hip_atomic_load(p, __ATOMIC_RELAXED, __HIP_MEMORY_SCOPE_AGENT);
      if (best < cur) atomicMin(p, best);
    }
  }
}

__device__ __forceinline__ int phase_b_dev(const unsigned long long* __restrict__ cbuf,
                                           int* scomp, unsigned long long* cl,
                                           int* pnew, int* sred,
                                           bool record, float* sdeaths, int* scnt) {
  const int t = threadIdx.x;
  for (int v = t; v < 1024; v += 256)
    cl[v] = __hip_atomic_load(&cbuf[v], __ATOMIC_RELAXED, __HIP_MEMORY_SCOPE_AGENT);
  if (t == 0) sred[0] = 0;
  __syncthreads();
  for (int v = t; v < 1024; v += 256) {
    int parent = scomp[v];
    if (parent == v) {
      const unsigned long long key = cl[v];
      if (key != ~0ull) {
        const int lo = (int)((key >> 10) & 1023), hi = (int)(key & 1023);
        const int clo = scomp[lo], chi = scomp[hi];
        const int other = (clo == v) ? chi : clo;
        const bool mutual = (cl[other] == key);
        if (record && (!mutual || v < other)) {
          const int pos = atomicAdd(scnt, 1);
          sdeaths[pos] = __uint_as_float((unsigned int)(key >> 32));
        }
        parent = (mutual && v < other) ? v : other;
      }
    }
    pnew[v] = parent;
  }
  __syncthreads();
#pragma unroll
  for (int it = 0; it < 2; ++it) {
    int q0 = pnew[pnew[t]];
    int q1 = pnew[pnew[t + 256]];
    int q2 = pnew[pnew[t + 512]];
    int q3 = pnew[pnew[t + 768]];
    __syncthreads();
    pnew[t] = q0; pnew[t + 256] = q1; pnew[t + 512] = q2; pnew[t + 768] = q3;
    __syncthreads();
  }
  int nroots = 0;
#pragma unroll
  for (int q = 0; q < 4; ++q) {
    const int v = t + q * 256;
    int p = pnew[v];
    while (p != pnew[p]) p = pnew[p];
    scomp[v] = p;
    if (p == v) ++nroots;
  }
  atomicAdd(&sred[0], nroots);
  __syncthreads();
  return sred[0];
}

__global__ __launch_bounds__(256) void fused_kernel(float* __restrict__ dist,
                                                    unsigned long long* __restrict__ cminb,
                                                    float* __restrict__ partials,
                                                    const float4* __restrict__ rx,
                                                    const float4* __restrict__ x,
                                                    const float4* __restrict__ mu,
                                                    const float4* __restrict__ lv,
                                                    float* __restrict__ out) {
  __shared__ int scomp[1024];
  __shared__ int pnew[1024];
  __shared__ unsigned long long cl[1024];
  __shared__ float sdeaths[1023];
  __shared__ int sred[2];              // [0] root count, [1] death count
  __shared__ float redf[12];
  const int t = threadIdx.x;
  const int b = blockIdx.x;
  int* done = (int*)(dist + 2 * 1025);          // diag (2,2), zeroed by dist

  // ======================= losses role: blocks 64..1087 ====================
  if (b >= PBLK) {
    const int lb = b - PBLK;
    const int base = lb * 4096 + t;
    float rs = 0.f;
#pragma unroll
    for (int kk = 0; kk < 4; ++kk) {
      const int i0 = base + kk * 1024;
      const float4 a0 = rx[i0],       c0 = x[i0];
      const float4 a1 = rx[i0 + 256], c1 = x[i0 + 256];
      const float4 a2 = rx[i0 + 512], c2 = x[i0 + 512];
      const float4 a3 = rx[i0 + 768], c3 = x[i0 + 768];
      rs += sub2(a0, c0) + sub2(a1, c1) + sub2(a2, c2) + sub2(a3, c3);
    }
    float ks = 0.f;
    if (lb < 256) {
      const int gid = lb * 256 + t;
      const float4 m = mu[gid], l = lv[gid];
      ks += 1.f + l.x - m.x * m.x - __expf(l.x);
      ks += 1.f + l.y - m.y * m.y - __expf(l.y);
      ks += 1.f + l.z - m.z * m.z - __expf(l.z);
      ks += 1.f + l.w - m.w * m.w - __expf(l.w);
    }
#pragma unroll
    for (int off = 32; off; off >>= 1) {
      rs += __shfl_xor(rs, off);
      ks += __shfl_xor(ks, off);
    }
    if ((t & 63) == 0) { redf[t >> 6] = rs; redf[4 + (t >> 6)] = ks; }
    __syncthreads();
    if (t == 0) {
      const float a = redf[0] + redf[1] + redf[2] + redf[3];
      const float c = redf[4] + redf[5] + redf[6] + redf[7];
      __hip_atomic_store((unsigned int*)&partials[lb], __float_as_uint(a),
                         __ATOMIC_RELAXED, __HIP_MEMORY_SCOPE_AGENT);
      __hip_atomic_store((unsigned int*)&partials[1024 + lb], __float_as_uint(c),
                         __ATOMIC_RELAXED, __HIP_MEMORY_SCOPE_AGENT);
      __hip_atomic_fetch_add(done, 1, __ATOMIC_RELEASE, __HIP_MEMORY_SCOPE_AGENT);
    }
    return;
  }

  // ======================= mst role: blocks 0..63 (R5 verbatim) ============
  const bool rec = (b == 0);
  int* slots = (int*)dist;             // slot b at diag (16b+1, 16b+1)

  for (int v = t; v < 1024; v += 256) scomp[v] = v;
  if (t == 0) sred[1] = 0;
  if (t < 16)                          // init buf2 slice
    __hip_atomic_store(&cminb[2048 + b * 16 + t], ~0ull,
                       __ATOMIC_RELAXED, __HIP_MEMORY_SCOPE_AGENT);
  __syncthreads();

  int ncomp = phase_b_dev(cminb, scomp, cl, pnew, sred, rec, sdeaths, &sred[1]);

  const int lane = t & 63;
  const int w = t >> 6;
  for (int r = 1; r < 10 && ncomp > 1; ++r) {
    unsigned long long* cbuf = cminb + (r % 3) * 1024;
    // ---- phase A: 16 rows per block (4 waves x 4 rows) ----
#pragma unroll
    for (int q = 0; q < 4; ++q) {
      const int i = b * 16 + w * 4 + q;
      const int ci = scomp[i];
      const float* row = dist + i * 1024;
      unsigned long long best = ~0ull;
#pragma unroll
      for (int k = 0; k < 4; ++k) {
        const int j0 = lane * 4 + k * 256;
        const float4 d4 = *(const float4*)(row + j0);
        const int4 c4 = *(const int4*)(&scomp[j0]);
        const float dv[4] = {d4.x, d4.y, d4.z, d4.w};
        const int cv[4] = {c4.x, c4.y, c4.z, c4.w};
#pragma unroll
        for (int c = 0; c < 4; ++c) {
          if (cv[c] != ci) {
            const int j = j0 + c;
            const int lo = i < j ? i : j;
            const int hi = i + j - lo;
            const unsigned long long key =
                ((unsigned long long)__float_as_uint(dv[c]) << 32)
              | (unsigned long long)((lo << 10) | hi);
            if (key < best) best = key;
          }
        }
      }
#pragma unroll
      for (int off = 32; off; off >>= 1) {
        const unsigned int blo = __shfl_xor((unsigned int)best, off);
        const unsigned int bhi = __shfl_xor((unsigned int)(best >> 32), off);
        const unsigned long long o = ((unsigned long long)bhi << 32) | blo;
        if (o < best) best = o;
      }
      if (lane == 0 && best != ~0ull) {
        const unsigned long long cur =
            __hip_atomic_load(&cbuf[ci], __ATOMIC_RELAXED, __HIP_MEMORY_SCOPE_AGENT);
        if (best < cur) atomicMin(&cbuf[ci], best);
      }
    }
    // ---- barrier r: parallel slot stores + wave-0 gather poll ----
    __syncthreads();
    if (t == 0)
      __hip_atomic_store(&slots[(size_t)(16 * b + 1) * 1025], r,
                         __ATOMIC_RELEASE, __HIP_MEMORY_SCOPE_AGENT);
    if (t < 64) {
      const size_t sidx = (size_t)(16 * t + 1) * 1025;
      for (;;) {
        const int v = __hip_atomic_load(&slots[sidx], __ATOMIC_ACQUIRE,
                                        __HIP_MEMORY_SCOPE_AGENT);
        if (__all(v >= r)) break;
        __builtin_amdgcn_s_sleep(1);
      }
    }
    __syncthreads();
    if (t < 16)
      __hip_atomic_store(&cminb[((r - 1) % 3) * 1024 + b * 16 + t], ~0ull,
                         __ATOMIC_RELAXED, __HIP_MEMORY_SCOPE_AGENT);
    ncomp = phase_b_dev(cbuf, scomp, cl, pnew, sred, rec, sdeaths, &sred[1]);
  }

  // ---------------- tail: silhouette + final (block 0 only) ----------------
  if (b != 0) return;
  if (t == 0) {                       // wait for losses role blocks
    while (__hip_atomic_load(done, __ATOMIC_ACQUIRE, __HIP_MEMORY_SCOPE_AGENT) < 1024)
      __builtin_amdgcn_s_sleep(2);
  }
  __syncthreads();
  float lmax = 0.f, lsum = 0.f;
  for (int v = t; v < 1023; v += 256) {
    const float d = sdeaths[v];
    lmax = fmaxf(lmax, d);
    lsum += d;
  }
#pragma unroll
  for (int off = 32; off; off >>= 1) {
    lmax = fmaxf(lmax, __shfl_xor(lmax, off));
    lsum += __shfl_xor(lsum, off);
  }
  if ((t & 63) == 0) { redf[t >> 6] = lmax; redf[4 + (t >> 6)] = lsum; }
  __syncthreads();
  const float tmax = fmaxf(fmaxf(redf[0], redf[1]), fmaxf(redf[2], redf[3]));
  const float wsum = redf[4] + redf[5] + redf[6] + redf[7];
  const float tt = (float)t * (1.0f / 255.0f) * tmax;
  float acc = 0.f;
  for (int j = 0; j < 1023; ++j) {
    const float dj = sdeaths[j];
    acc += dj * fmaxf(fminf(tt, dj - tt), 0.f);
  }
  float phi = acc / (wsum + 1e-12f);
  float rs = 0.f, ks = 0.f;
  for (int v = t; v < 1024; v += 256) {
    rs += __uint_as_float(__hip_atomic_load((const unsigned int*)&partials[v],
                                            __ATOMIC_RELAXED, __HIP_MEMORY_SCOPE_AGENT));
    ks += __uint_as_float(__hip_atomic_load((const unsigned int*)&partials[1024 + v],
                                            __ATOMIC_RELAXED, __HIP_MEMORY_SCOPE_AGENT));
  }
#pragma unroll
  for (int off = 32; off; off >>= 1) {
    phi += __shfl_xor(phi, off);
    rs += __shfl_xor(rs, off);
    ks += __shfl_xor(ks, off);
  }
  __syncthreads();
  if ((t & 63) == 0) { redf[t >> 6] = phi; redf[4 + (t >> 6)] = rs; redf[8 + (t >> 6)] = ks; }
  __syncthreads();
  if (t == 0) {
    const float topo = (redf[0] + redf[1] + redf[2] + redf[3]) * (1.f / 256.f);
    const float recon = (redf[4] + redf[5] + redf[6] + redf[7]) * (1.f / 16777216.f);
    const float kl = -0.5f * (redf[8] + redf[9] + redf[10] + redf[11]) * (1.f / 262144.f);
    const float total = recon + 0.1f * kl + 0.5f * topo;
    out[0] = (float)__float2bfloat16(total);
    out[1] = (float)__float2bfloat16(recon);
    out[2] = (float)__float2bfloat16(kl);
    out[3] = (float)__float2bfloat16(topo);
  }
}

extern "C" void kernel_launch(void* const* d_in, const int* in_sizes, int n_in,
                              void* d_out, int out_size, void* d_ws, size_t ws_size,
                              hipStream_t stream) {
  const float* rx = (const float*)d_in[0];
  const float* x  = (const float*)d_in[1];
  const float* mu = (const float*)d_in[2];
  const float* lv = (const float*)d_in[3];
  const float* z  = (const float*)d_in[4];

  float* wsf = (float*)d_ws;
  unsigned long long* cminb = (unsigned long long*)wsf;    // 3 x u64[1024]
  float* partials = wsf + 6144;                            // 2048 floats
  float* dist     = wsf + 8192;                            // 4 MB
  float* out      = (float*)d_out;

  init_kernel<<<1, 256, 0, stream>>>(cminb);
  dist_kernel<<<256, 256, 0, stream>>>(z, dist, cminb);
  fused_kernel<<<NBLK + PBLK, 256, 0, stream>>>(dist, cminb, partials,
                                                (const float4*)rx, (const float4*)x,
                                                (const float4*)mu, (const float4*)lv,
                                                out);
}

// Round 7
// 205.138 us; speedup vs baseline: 1.2830x; 1.2830x over previous
//
#include <hip/hip_runtime.h>
#include <hip/hip_bf16.h>
#include <math.h>

// ---------------------------------------------------------------------------
// B=1024, D_DATA=16384, D_LAT=256, N_GRID=256. Inputs f32.
// d_out = f32 slots; harness reads high u16 of each slot as bf16 -> store
// (float)__float2bfloat16(v) (proven R6).
//
// Structure (3 launches):
//   init_kernel : 1x256, cmin buf0/buf1 = ~0.
//   prep_kernel : 1280x256. Blocks 0..255 = dist tiles (self-computed row
//                 norms, diag=0 -> barrier slots, fused Boruvka round-0
//                 phase A into cmin buf0). Blocks 256..1279 = losses
//                 (recon/kl partials, 16 float4/thread, 4 independent
//                 accumulators for deep MLP). dist is VALU/LDS-bound and
//                 hides under the BW-bound losses. SAFE fusion: nothing
//                 latency-bound runs concurrently (R6 lesson: mst's LLC
//                 chain slowed 2.4x under co-residency -> mst stays serial).
//   mst_kernel  : 64x256 persistent Boruvka (R5 verbatim, proven 54.5us):
//                 comp in LDS, redundant deterministic phase B, slot barrier
//                 (per-block release store + wave-0 gather poll), cmin
//                 buffers rotate mod 3. Block 0 tail: silhouette + final.
//
// Fixed harness overhead is ~110us regardless of launch count (R0 25
// launches vs R3/R5 3 launches: same gap) -> only kernel time matters.
//
// ws layout (floats):
//   [0..2047]    cmin buf0 (u64[1024])  init by init_kernel
//   [2048..4095] cmin buf1 (u64[1024])  init by init_kernel
//   [4096..6143] cmin buf2 (u64[1024])  init by mst blocks at start
//   [6144..8191] partials (recon 1024 | kl 1024)
//   [8192..]     dist 1024x1024 (4 MB); diag (16b+1,16b+1) barrier slots
//                (zeroed by prep dist role; diag never read as distances:
//                phase A skips comp[j]==comp[i])
// ---------------------------------------------------------------------------

#define NBLK 1024
#define PBLK 64
#define DBLK 256   // dist-role blocks in prep_kernel

__device__ __forceinline__ float sub2(const float4 a, const float4 b) {
  const float dx = a.x - b.x, dy = a.y - b.y, dz = a.z - b.z, dw = a.w - b.w;
  return dx * dx + dy * dy + dz * dz + dw * dw;
}

__global__ __launch_bounds__(256) void init_kernel(unsigned long long* __restrict__ cminb) {
  const int t = threadIdx.x;
  for (int v = t; v < 2048; v += 256) cminb[v] = ~0ull;
}

__global__ __launch_bounds__(256) void prep_kernel(const float* __restrict__ z,
                                                   float* __restrict__ dist,
                                                   unsigned long long* __restrict__ cmin0,
                                                   const float4* __restrict__ rx,
                                                   const float4* __restrict__ x,
                                                   const float4* __restrict__ mu,
                                                   const float4* __restrict__ lv,
                                                   float* __restrict__ partials) {
  __shared__ float A[64][68];
  __shared__ float Bs[64][68];
  __shared__ float sqA[64];
  __shared__ float sqB[64];
  __shared__ float red[8];
  const int t = threadIdx.x;
  const int b = blockIdx.x;

  // ======================= losses role: blocks 256..1279 ===================
  if (b >= DBLK) {
    const int lb = b - DBLK;
    const int base = lb * 4096 + t;
    float rs0 = 0.f, rs1 = 0.f, rs2 = 0.f, rs3 = 0.f;
#pragma unroll
    for (int kk = 0; kk < 4; ++kk) {
      const int i0 = base + kk * 1024;
      const float4 a0 = rx[i0],       c0 = x[i0];
      const float4 a1 = rx[i0 + 256], c1 = x[i0 + 256];
      const float4 a2 = rx[i0 + 512], c2 = x[i0 + 512];
      const float4 a3 = rx[i0 + 768], c3 = x[i0 + 768];
      rs0 += sub2(a0, c0);
      rs1 += sub2(a1, c1);
      rs2 += sub2(a2, c2);
      rs3 += sub2(a3, c3);
    }
    float rs = (rs0 + rs1) + (rs2 + rs3);
    float ks = 0.f;
    if (lb < 256) {
      const int gid = lb * 256 + t;
      const float4 m = mu[gid], l = lv[gid];
      ks += 1.f + l.x - m.x * m.x - __expf(l.x);
      ks += 1.f + l.y - m.y * m.y - __expf(l.y);
      ks += 1.f + l.z - m.z * m.z - __expf(l.z);
      ks += 1.f + l.w - m.w * m.w - __expf(l.w);
    }
#pragma unroll
    for (int off = 32; off; off >>= 1) {
      rs += __shfl_xor(rs, off);
      ks += __shfl_xor(ks, off);
    }
    if ((t & 63) == 0) { red[t >> 6] = rs; red[4 + (t >> 6)] = ks; }
    __syncthreads();
    if (t == 0) {
      partials[lb] = red[0] + red[1] + red[2] + red[3];
      partials[NBLK + lb] = red[4] + red[5] + red[6] + red[7];
    }
    return;
  }

  // ======================= dist role: blocks 0..255 ========================
  const int i0 = (b >> 4) * 64, j0 = (b & 15) * 64;
  const int tx = t & 15;
  const int ty = t >> 4;
  float acc[4][4] = {};
  float psA = 0.f, psB = 0.f;          // per-thread row-norm partials
  const int sr = t >> 2, sc = (t & 3) * 16;
  for (int k0 = 0; k0 < 256; k0 += 64) {
    __syncthreads();
#pragma unroll
    for (int it = 0; it < 4; ++it) {
      int lin = it * 256 + t;
      int row = lin >> 4, q = lin & 15;
      *(float4*)&A[row][q * 4]  = *(const float4*)(z + (i0 + row) * 256 + k0 + q * 4);
      *(float4*)&Bs[row][q * 4] = *(const float4*)(z + (j0 + row) * 256 + k0 + q * 4);
    }
    __syncthreads();
#pragma unroll
    for (int e = 0; e < 16; ++e) {
      const float va = A[sr][sc + e];  psA += va * va;
      const float vb = Bs[sr][sc + e]; psB += vb * vb;
    }
#pragma unroll 4
    for (int k = 0; k < 64; k += 4) {
      float4 av[4], bv[4];
#pragma unroll
      for (int rr = 0; rr < 4; ++rr) av[rr] = *(const float4*)&A[ty + 16 * rr][k];
#pragma unroll
      for (int cc = 0; cc < 4; ++cc) bv[cc] = *(const float4*)&Bs[tx + 16 * cc][k];
#pragma unroll
      for (int rr = 0; rr < 4; ++rr)
#pragma unroll
        for (int cc = 0; cc < 4; ++cc) {
          acc[rr][cc] += av[rr].x * bv[cc].x;
          acc[rr][cc] += av[rr].y * bv[cc].y;
          acc[rr][cc] += av[rr].z * bv[cc].z;
          acc[rr][cc] += av[rr].w * bv[cc].w;
        }
    }
  }
  {
    float s = psA + __shfl_xor(psA, 1); s += __shfl_xor(s, 2);
    if ((t & 3) == 0) sqA[t >> 2] = s;
    float u = psB + __shfl_xor(psB, 1); u += __shfl_xor(u, 2);
    if ((t & 3) == 0) sqB[t >> 2] = u;
  }
  __syncthreads();
  unsigned long long rowbest[4] = {~0ull, ~0ull, ~0ull, ~0ull};
#pragma unroll
  for (int rr = 0; rr < 4; ++rr) {
    const int i = i0 + ty + 16 * rr;
    const float sqi = sqA[ty + 16 * rr];
#pragma unroll
    for (int cc = 0; cc < 4; ++cc) {
      const int j = j0 + tx + 16 * cc;
      const float d2 = sqi + sqB[tx + 16 * cc] - 2.f * acc[rr][cc];
      const float d = sqrtf(fmaxf(d2, 0.f) + 1e-12f);
      dist[i * 1024 + j] = (j == i) ? 0.f : d;
      if (j != i) {
        const int lo = i < j ? i : j;
        const int hi = i + j - lo;
        const unsigned long long key =
            ((unsigned long long)__float_as_uint(d) << 32)
          | (unsigned long long)((lo << 10) | hi);
        if (key < rowbest[rr]) rowbest[rr] = key;
      }
    }
  }
#pragma unroll
  for (int rr = 0; rr < 4; ++rr) {
    unsigned long long best = rowbest[rr];
#pragma unroll
    for (int off = 8; off; off >>= 1) {
      const unsigned int blo = __shfl_xor((unsigned int)best, off);
      const unsigned int bhi = __shfl_xor((unsigned int)(best >> 32), off);
      const unsigned long long o = ((unsigned long long)bhi << 32) | blo;
      if (o < best) best = o;
    }
    if (tx == 0) {
      unsigned long long* p = &cmin0[i0 + ty + 16 * rr];
      const unsigned long long cur =
          __hip_atomic_load(p, __ATOMIC_RELAXED, __HIP_MEMORY_SCOPE_AGENT);
      if (best < cur) atomicMin(p, best);
    }
  }
}

__device__ __forceinline__ int phase_b_dev(const unsigned long long* __restrict__ cbuf,
                                           int* scomp, unsigned long long* cl,
                                           int* pnew, int* sred,
                                           bool record, float* sdeaths, int* scnt) {
  const int t = threadIdx.x;
  for (int v = t; v < 1024; v += 256)
    cl[v] = __hip_atomic_load(&cbuf[v], __ATOMIC_RELAXED, __HIP_MEMORY_SCOPE_AGENT);
  if (t == 0) sred[0] = 0;
  __syncthreads();
  for (int v = t; v < 1024; v += 256) {
    int parent = scomp[v];
    if (parent == v) {
      const unsigned long long key = cl[v];
      if (key != ~0ull) {
        const int lo = (int)((key >> 10) & 1023), hi = (int)(key & 1023);
        const int clo = scomp[lo], chi = scomp[hi];
        const int other = (clo == v) ? chi : clo;
        const bool mutual = (cl[other] == key);
        if (record && (!mutual || v < other)) {
          const int pos = atomicAdd(scnt, 1);
          sdeaths[pos] = __uint_as_float((unsigned int)(key >> 32));
        }
        parent = (mutual && v < other) ? v : other;
      }
    }
    pnew[v] = parent;
  }
  __syncthreads();
#pragma unroll
  for (int it = 0; it < 2; ++it) {
    int q0 = pnew[pnew[t]];
    int q1 = pnew[pnew[t + 256]];
    int q2 = pnew[pnew[t + 512]];
    int q3 = pnew[pnew[t + 768]];
    __syncthreads();
    pnew[t] = q0; pnew[t + 256] = q1; pnew[t + 512] = q2; pnew[t + 768] = q3;
    __syncthreads();
  }
  int nroots = 0;
#pragma unroll
  for (int q = 0; q < 4; ++q) {
    const int v = t + q * 256;
    int p = pnew[v];
    while (p != pnew[p]) p = pnew[p];
    scomp[v] = p;
    if (p == v) ++nroots;
  }
  atomicAdd(&sred[0], nroots);
  __syncthreads();
  return sred[0];
}

__global__ __launch_bounds__(256) void mst_kernel(float* __restrict__ dist,
                                                  unsigned long long* __restrict__ cminb,
                                                  const float* __restrict__ partials,
                                                  float* __restrict__ out) {
  __shared__ int scomp[1024];
  __shared__ int pnew[1024];
  __shared__ unsigned long long cl[1024];
  __shared__ float sdeaths[1023];
  __shared__ int sred[2];              // [0] root count, [1] death count
  __shared__ float redf[12];
  const int t = threadIdx.x;
  const int b = blockIdx.x;
  const bool rec = (b == 0);
  int* slots = (int*)dist;             // slot b at diag (16b+1, 16b+1)

  for (int v = t; v < 1024; v += 256) scomp[v] = v;
  if (t == 0) sred[1] = 0;
  if (t < 16)                          // init buf2 slice
    __hip_atomic_store(&cminb[2048 + b * 16 + t], ~0ull,
                       __ATOMIC_RELAXED, __HIP_MEMORY_SCOPE_AGENT);
  __syncthreads();

  int ncomp = phase_b_dev(cminb, scomp, cl, pnew, sred, rec, sdeaths, &sred[1]);

  const int lane = t & 63;
  const int w = t >> 6;
  for (int r = 1; r < 10 && ncomp > 1; ++r) {
    unsigned long long* cbuf = cminb + (r % 3) * 1024;
    // ---- phase A: 16 rows per block (4 waves x 4 rows) ----
#pragma unroll
    for (int q = 0; q < 4; ++q) {
      const int i = b * 16 + w * 4 + q;
      const int ci = scomp[i];
      const float* row = dist + i * 1024;
      unsigned long long best = ~0ull;
#pragma unroll
      for (int k = 0; k < 4; ++k) {
        const int j0 = lane * 4 + k * 256;
        const float4 d4 = *(const float4*)(row + j0);
        const int4 c4 = *(const int4*)(&scomp[j0]);
        const float dv[4] = {d4.x, d4.y, d4.z, d4.w};
        const int cv[4] = {c4.x, c4.y, c4.z, c4.w};
#pragma unroll
        for (int c = 0; c < 4; ++c) {
          if (cv[c] != ci) {
            const int j = j0 + c;
            const int lo = i < j ? i : j;
            const int hi = i + j - lo;
            const unsigned long long key =
                ((unsigned long long)__float_as_uint(dv[c]) << 32)
              | (unsigned long long)((lo << 10) | hi);
            if (key < best) best = key;
          }
        }
      }
#pragma unroll
      for (int off = 32; off; off >>= 1) {
        const unsigned int blo = __shfl_xor((unsigned int)best, off);
        const unsigned int bhi = __shfl_xor((unsigned int)(best >> 32), off);
        const unsigned long long o = ((unsigned long long)bhi << 32) | blo;
        if (o < best) best = o;
      }
      if (lane == 0 && best != ~0ull) {
        const unsigned long long cur =
            __hip_atomic_load(&cbuf[ci], __ATOMIC_RELAXED, __HIP_MEMORY_SCOPE_AGENT);
        if (best < cur) atomicMin(&cbuf[ci], best);
      }
    }
    // ---- barrier r: parallel slot stores + wave-0 gather poll ----
    __syncthreads();
    if (t == 0)
      __hip_atomic_store(&slots[(size_t)(16 * b + 1) * 1025], r,
                         __ATOMIC_RELEASE, __HIP_MEMORY_SCOPE_AGENT);
    if (t < 64) {
      const size_t sidx = (size_t)(16 * t + 1) * 1025;
      for (;;) {
        const int v = __hip_atomic_load(&slots[sidx], __ATOMIC_ACQUIRE,
                                        __HIP_MEMORY_SCOPE_AGENT);
        if (__all(v >= r)) break;
        __builtin_amdgcn_s_sleep(1);
      }
    }
    __syncthreads();
    if (t < 16)
      __hip_atomic_store(&cminb[((r - 1) % 3) * 1024 + b * 16 + t], ~0ull,
                         __ATOMIC_RELAXED, __HIP_MEMORY_SCOPE_AGENT);
    ncomp = phase_b_dev(cbuf, scomp, cl, pnew, sred, rec, sdeaths, &sred[1]);
  }

  // ---------------- tail: silhouette + final (block 0 only) ----------------
  if (b != 0) return;
  float lmax = 0.f, lsum = 0.f;
  for (int v = t; v < 1023; v += 256) {
    const float d = sdeaths[v];
    lmax = fmaxf(lmax, d);
    lsum += d;
  }
#pragma unroll
  for (int off = 32; off; off >>= 1) {
    lmax = fmaxf(lmax, __shfl_xor(lmax, off));
    lsum += __shfl_xor(lsum, off);
  }
  if ((t & 63) == 0) { redf[t >> 6] = lmax; redf[4 + (t >> 6)] = lsum; }
  __syncthreads();
  const float tmax = fmaxf(fmaxf(redf[0], redf[1]), fmaxf(redf[2], redf[3]));
  const float wsum = redf[4] + redf[5] + redf[6] + redf[7];
  const float tt = (float)t * (1.0f / 255.0f) * tmax;
  float acc = 0.f;
  for (int j = 0; j < 1023; ++j) {
    const float dj = sdeaths[j];
    acc += dj * fmaxf(fminf(tt, dj - tt), 0.f);
  }
  float phi = acc / (wsum + 1e-12f);
  float rs = 0.f, ks = 0.f;
  for (int v = t; v < 1024; v += 256) { rs += partials[v]; ks += partials[1024 + v]; }
#pragma unroll
  for (int off = 32; off; off >>= 1) {
    phi += __shfl_xor(phi, off);
    rs += __shfl_xor(rs, off);
    ks += __shfl_xor(ks, off);
  }
  __syncthreads();
  if ((t & 63) == 0) { redf[t >> 6] = phi; redf[4 + (t >> 6)] = rs; redf[8 + (t >> 6)] = ks; }
  __syncthreads();
  if (t == 0) {
    const float topo = (redf[0] + redf[1] + redf[2] + redf[3]) * (1.f / 256.f);
    const float recon = (redf[4] + redf[5] + redf[6] + redf[7]) * (1.f / 16777216.f);
    const float kl = -0.5f * (redf[8] + redf[9] + redf[10] + redf[11]) * (1.f / 262144.f);
    const float total = recon + 0.1f * kl + 0.5f * topo;
    out[0] = (float)__float2bfloat16(total);
    out[1] = (float)__float2bfloat16(recon);
    out[2] = (float)__float2bfloat16(kl);
    out[3] = (float)__float2bfloat16(topo);
  }
}

extern "C" void kernel_launch(void* const* d_in, const int* in_sizes, int n_in,
                              void* d_out, int out_size, void* d_ws, size_t ws_size,
                              hipStream_t stream) {
  const float* rx = (const float*)d_in[0];
  const float* x  = (const float*)d_in[1];
  const float* mu = (const float*)d_in[2];
  const float* lv = (const float*)d_in[3];
  const float* z  = (const float*)d_in[4];

  float* wsf = (float*)d_ws;
  unsigned long long* cminb = (unsigned long long*)wsf;    // 3 x u64[1024]
  float* partials = wsf + 6144;                            // 2048 floats
  float* dist     = wsf + 8192;                            // 4 MB
  float* out      = (float*)d_out;

  init_kernel<<<1, 256, 0, stream>>>(cminb);
  prep_kernel<<<NBLK + DBLK, 256, 0, stream>>>(z, dist, cminb,
                                               (const float4*)rx, (const float4*)x,
                                               (const float4*)mu, (const float4*)lv,
                                               partials);
  mst_kernel<<<PBLK, 256, 0, stream>>>(dist, cminb, partials, out);
}